// Round 18
// baseline (364.143 us; speedup 1.0000x reference)
//
#include <hip/hip_runtime.h>
#include <cstdint>

#define NROW 66560   // 2*NX + J rows through both MLPs
#define NXP  32768   // nx
#define NV   1024    // J
#define FD   100     // dn output dim
#define GD   28      // input / an output dim
#define HD   300     // hidden dim
#define HP   320     // padded hidden dim
#define SAMP 96      // samples per block (MLP)
#define NT   6       // sample tiles
#define NCH  10      // K chunks (320/32)
#define FKP  128     // f padded K for dist MFMA
#define GKP  32      // g padded K
#define CSTR 32      // colsum stripes
#define NXBLK (NROW * 32 / 256)   // 8320 prep_x blocks
#define NWBLK 400                 // blocks per weight matrix (102400/256)
#define DBLK (NXP / 64 * NV / 64) // 8192 dist2 blocks (1D, XCD-swizzled)

typedef unsigned short u16;
typedef __bf16    bf16x8 __attribute__((ext_vector_type(8)));
typedef _Float16  f16x8  __attribute__((ext_vector_type(8)));
typedef float     f32x4  __attribute__((ext_vector_type(4)));

__device__ inline u16 f2bf(float x) {
  unsigned u = __builtin_bit_cast(unsigned, x);
  unsigned r = (u + 0x7FFF + ((u >> 16) & 1)) >> 16;
  return (u16)r;
}
__device__ inline float bf2f(u16 h) {
  unsigned u = ((unsigned)h) << 16;
  return __builtin_bit_cast(float, u);
}
// HW packed f32->bf16 RNE.
__device__ inline unsigned cvt_pk_bf16(float lo, float hi) {
  unsigned r;
  asm("v_cvt_pk_bf16_f32 %0, %1, %2" : "=v"(r) : "v"(lo), "v"(hi));
  return r;
}
// RNE f32->fp16 pair pack.
__device__ inline unsigned pk_f16(float a, float b) {
  unsigned ua = (unsigned)__builtin_bit_cast(u16, (_Float16)a);
  unsigned ub = (unsigned)__builtin_bit_cast(u16, (_Float16)b);
  return ua | (ub << 16);
}
__device__ inline float f16tof(u16 h) {
  return (float)__builtin_bit_cast(_Float16, h);
}

// ---------------------------------------------------------------------------
// prep_all: fused prep_x + prep_w + zero-fill. All MLP planes fp16.
// BIAS-FOLD: weight row k==K holds bias[m]; activation col K holds 1.0.
// ---------------------------------------------------------------------------
struct WDesc { const float* W; const float* b; u16* hi; int K, M, Kpad, Mpad; };
struct PrepArgs {
  const float* XY; const float* V; u16* Xhi; float* Xf;
  WDesc d[12];
  char* zbase; unsigned zbytes;
};

__global__ __launch_bounds__(256) void prep_all(PrepArgs a)
{
  const int tid = threadIdx.x;
  const int bid = blockIdx.x;
  if (bid < NXBLK) {
    int gid = bid * 256 + tid;
    int row = gid >> 5, k = gid & 31;
    if (row >= NROW) return;
    float v = 0.f;
    if (k < GD) v = (row < 2 * NXP) ? a.XY[(size_t)row * GD + k]
                                    : a.V[(size_t)(row - 2 * NXP) * GD + k];
    else if (k == GD) v = 1.f;   // bias column for layer 0/6
    size_t off = (size_t)(row >> 4) * 512 + (size_t)(k >> 3) * 128
               + (size_t)(row & 15) * 8 + (k & 7);
    a.Xhi[off] = __builtin_bit_cast(u16, (_Float16)v);
    if (k < GD) a.Xf[(size_t)row * GD + k] = v;
  } else if (bid < NXBLK + 12 * NWBLK) {
    int r = bid - NXBLK;
    WDesc d = a.d[r / NWBLK];
    int gid = (r % NWBLK) * 256 + tid;
    if (gid >= d.Kpad * d.Mpad) return;
    int e = gid & 7, l = (gid >> 3) & 63, rest = gid >> 9;
    int nch = d.Kpad >> 5;
    int ch = rest % nch, t = rest / nch;
    int m = t * 16 + (l & 15);
    int k = ch * 32 + (l >> 4) * 8 + e;
    float v = 0.f;
    if (m < d.M) {
      if (k < d.K)       v = d.W[(size_t)k * d.M + m];
      else if (k == d.K) v = d.b[m];          // folded bias row
    }
    d.hi[gid] = __builtin_bit_cast(u16, (_Float16)v);
  } else {
    int r = bid - NXBLK - 12 * NWBLK;
    size_t off16 = ((size_t)r * 256 + tid) * 16;
    if (off16 < a.zbytes) {
      uint4 z = {0u, 0u, 0u, 0u};
      *reinterpret_cast<uint4*>(a.zbase + off16) = z;
    }
  }
}

// ---------------------------------------------------------------------------
// Fused MLP v21 (R15-proven, 125us): fp16 interior + bias-folded weights.
// ---------------------------------------------------------------------------
template<int MT>
__device__ __forceinline__ void mm6(
    const u16* __restrict__ Wh, const u16* aH,
    f32x4 (&acc)[3][NT], int tile0, int lane)
{
#pragma unroll
  for (int mt = 0; mt < MT; ++mt)
#pragma unroll
    for (int nt = 0; nt < NT; ++nt) acc[mt][nt] = (f32x4)0.f;
#pragma unroll 2
  for (int ch = 0; ch < NCH; ++ch) {
    f16x8 wh[MT];
#pragma unroll
    for (int mt = 0; mt < MT; ++mt) {
      size_t wo = ((size_t)((tile0 + mt) * NCH + ch) * 64 + lane) * 8;
      wh[mt] = *reinterpret_cast<const f16x8*>(&Wh[wo]);
    }
#pragma unroll
    for (int g = 0; g < 3; ++g) {
      f16x8 bh[2];
#pragma unroll
      for (int n2 = 0; n2 < 2; ++n2)
        bh[n2] = *reinterpret_cast<const f16x8*>(
            &aH[(((g * 2 + n2) * NCH + ch) * 64 + lane) * 8]);
#pragma unroll
      for (int mt = 0; mt < MT; ++mt)
#pragma unroll
        for (int n2 = 0; n2 < 2; ++n2)
          acc[mt][g * 2 + n2] = __builtin_amdgcn_mfma_f32_16x16x32_f16(wh[mt], bh[n2], acc[mt][g * 2 + n2], 0, 0, 0);
    }
  }
}

template<int MT>
__device__ __forceinline__ void mm6_in(
    const u16* __restrict__ Wh,
    const u16* __restrict__ Xhi, int rowt0,
    f32x4 (&acc)[3][NT], int tile0, int lane)
{
#pragma unroll
  for (int mt = 0; mt < MT; ++mt)
#pragma unroll
    for (int nt = 0; nt < NT; ++nt) acc[mt][nt] = (f32x4)0.f;
  f16x8 wh[MT];
#pragma unroll
  for (int mt = 0; mt < MT; ++mt) {
    size_t wo = ((size_t)(tile0 + mt) * 64 + lane) * 8;
    wh[mt] = *reinterpret_cast<const f16x8*>(&Wh[wo]);
  }
#pragma unroll
  for (int g = 0; g < 3; ++g) {
    f16x8 bh[2];
#pragma unroll
    for (int n2 = 0; n2 < 2; ++n2) {
      int st = g * 2 + n2;
      bh[n2] = *reinterpret_cast<const f16x8*>(&Xhi[((size_t)(rowt0 + st) * 64 + lane) * 8]);
    }
#pragma unroll
    for (int mt = 0; mt < MT; ++mt)
#pragma unroll
      for (int n2 = 0; n2 < 2; ++n2)
        acc[mt][g * 2 + n2] = __builtin_amdgcn_mfma_f32_16x16x32_f16(wh[mt], bh[n2], acc[mt][g * 2 + n2], 0, 0, 0);
  }
}

// Epilogue: ReLU + fp16 pack only (bias folded). feat==HD gets 1.0.
template<int MT>
__device__ __forceinline__ void epi6(
    f32x4 (&acc)[3][NT],
    u16* aH, int tile0, int m16, int quad)
{
#pragma unroll
  for (int mt = 0; mt < MT; ++mt) {
    int T = tile0 + mt;
    int ch = T >> 1;
    int lfrag = m16 + 16 * ((T & 1) * 2 + (quad >> 1));
    int e0 = (quad & 1) * 4;
    bool biasCol = (T * 16 + quad * 4 == HD);   // feat 300 in this pack's r=0
#pragma unroll
    for (int nt = 0; nt < NT; ++nt) {
      uint2 d;
      d.x = pk_f16(fmaxf(acc[mt][nt][0], 0.f), fmaxf(acc[mt][nt][1], 0.f));
      d.y = pk_f16(fmaxf(acc[mt][nt][2], 0.f), fmaxf(acc[mt][nt][3], 0.f));
      if (biasCol) d.x = (d.x & 0xFFFF0000u) | 0x3C00u;   // feat 300 = 1.0
      *reinterpret_cast<uint2*>(&aH[((nt * NCH + ch) * 64 + lfrag) * 8 + e0]) = d;
    }
  }
}

__global__ __launch_bounds__(512, 4) void mlp_fused(
    const u16* __restrict__ Xhi, const float* __restrict__ Xf,
    const u16* __restrict__ Whi,
    u16* __restrict__ fh, u16* __restrict__ gh,
    float* __restrict__ fn, float* __restrict__ gn)
{
  __shared__ u16 aH[NT * NCH * 64 * 8];   // 61,440 B
  __shared__ float nP[8][SAMP];           // +3,072 B -> 64.5KB: 2 blocks/CU
  const int tid  = threadIdx.x;
  const int wave = tid >> 6, lane = tid & 63;
  const int m16  = lane & 15, quad = lane >> 4;
  const int half  = blockIdx.x & 1;          // 0 = dn MLP, 1 = an MLP
  const int chunk = blockIdx.x >> 1;
  const int row0 = (chunk * SAMP + SAMP <= NROW) ? chunk * SAMP
                                                 : NROW - SAMP;  // overlap-safe
  const int rowt0  = row0 >> 4;
  const int ftile0 = (wave < 4) ? wave * 48 : 192 + (wave - 4) * 32;
  const int tile0  = ftile0 >> 4;

  auto W = [&](int s) { return Whi + (size_t)s * HP * HP; };

  f32x4 acc[3][NT];

  if (half == 0) {
    // ---- dn MLP ----
    if (wave < 4) mm6_in<3>(W(0), Xhi, rowt0, acc, tile0, lane);
    else          mm6_in<2>(W(0), Xhi, rowt0, acc, tile0, lane);
    if (wave < 4) epi6<3>(acc, aH, tile0, m16, quad);
    else          epi6<2>(acc, aH, tile0, m16, quad);
    __syncthreads();
#pragma unroll 1
    for (int s = 1; s <= 4; ++s) {
      if (wave < 4) mm6<3>(W(s), aH, acc, tile0, lane);
      else          mm6<2>(W(s), aH, acc, tile0, lane);
      __syncthreads();
      if (wave < 4) epi6<3>(acc, aH, tile0, m16, quad);
      else          epi6<2>(acc, aH, tile0, m16, quad);
      __syncthreads();
    }
    // layer 5 + fused f-norms; store single fp16 f plane (bias folded)
    mm6<1>(W(5), aH, acc, wave, lane);
    int chf = wave >> 1;
    int lfrag = m16 + 16 * ((wave * 2 + (quad >> 1)) & 3);
    int e0 = (quad & 1) * 4;
#pragma unroll
    for (int nt = 0; nt < NT; ++nt) {
      uint2 hp;
      hp.x = pk_f16(acc[0][nt][0], acc[0][nt][1]);
      hp.y = pk_f16(acc[0][nt][2], acc[0][nt][3]);
      size_t o = ((size_t)((rowt0 + nt) * 4 + chf) * 64 + lfrag) * 8 + e0;
      *reinterpret_cast<uint2*>(&fh[o]) = hp;
      float a0 = f16tof((u16)(hp.x & 0xFFFF)), a1 = f16tof((u16)(hp.x >> 16));
      float a2 = f16tof((u16)(hp.y & 0xFFFF)), a3 = f16tof((u16)(hp.y >> 16));
      float pf = a0 * a0 + a1 * a1 + a2 * a2 + a3 * a3;
      pf += __shfl_xor(pf, 16);
      pf += __shfl_xor(pf, 32);
      if (quad == 0) nP[wave][nt * 16 + m16] = pf;
    }
    __syncthreads();
    if (tid < SAMP) {
      float s = 0.f;
#pragma unroll
      for (int w8 = 0; w8 < 8; ++w8) s += nP[w8][tid];
      fn[row0 + tid] = s;
    }
  } else {
    // ---- an MLP ----
    if (wave < 4) mm6_in<3>(W(6), Xhi, rowt0, acc, tile0, lane);
    else          mm6_in<2>(W(6), Xhi, rowt0, acc, tile0, lane);
    if (wave < 4) epi6<3>(acc, aH, tile0, m16, quad);
    else          epi6<2>(acc, aH, tile0, m16, quad);
    __syncthreads();
#pragma unroll 1
    for (int s = 7; s <= 10; ++s) {
      if (wave < 4) mm6<3>(W(s), aH, acc, tile0, lane);
      else          mm6<2>(W(s), aH, acc, tile0, lane);
      __syncthreads();
      if (wave < 4) epi6<3>(acc, aH, tile0, m16, quad);
      else          epi6<2>(acc, aH, tile0, m16, quad);
      __syncthreads();
    }
    // layer 11 + fused g-norms; store single fp16 g plane (bias folded)
    if (wave < 2) {
      mm6<1>(W(11), aH, acc, wave, lane);
      int c = wave * 16 + quad * 4;
      int lfrag = m16 + 16 * ((wave * 2 + (quad >> 1)) & 3);
      int e0 = (quad & 1) * 4;
#pragma unroll
      for (int nt = 0; nt < NT; ++nt) {
        int samp = nt * 16 + m16;
        float x[4];
#pragma unroll
        for (int r = 0; r < 4; ++r) {
          int feat = c + r;
          x[r] = (feat < GD)
               ? acc[0][nt][r] + Xf[(size_t)(row0 + samp) * GD + feat]
               : 0.f;
        }
        uint2 hp;
        hp.x = pk_f16(x[0], x[1]);
        hp.y = pk_f16(x[2], x[3]);
        size_t o = ((size_t)(rowt0 + nt) * 64 + lfrag) * 8 + e0;
        *reinterpret_cast<uint2*>(&gh[o]) = hp;
        float a0 = f16tof((u16)(hp.x & 0xFFFF)), a1 = f16tof((u16)(hp.x >> 16));
        float a2 = f16tof((u16)(hp.y & 0xFFFF)), a3 = f16tof((u16)(hp.y >> 16));
        float pg = a0 * a0 + a1 * a1 + a2 * a2 + a3 * a3;
        pg += __shfl_xor(pg, 16);
        pg += __shfl_xor(pg, 32);
        if (quad == 0) nP[wave][nt * 16 + m16] = pg;
      }
    }
    __syncthreads();
    if (tid < SAMP) gn[row0 + tid] = nP[0][tid] + nP[1][tid];
  }
}

// ---------------------------------------------------------------------------
// Dist pass v4: 1D grid, j-FAST flatten + chunked XCD swizzle (T1).
// Each XCD executes contiguous i-tile runs with full 16-j sweeps -> each
// 48KB X/Y tile is fetched into ONE XCD's L2 once, reused 16x back-to-back.
// Numerics identical to R15 (pure index remap).
// ---------------------------------------------------------------------------
__global__ __launch_bounds__(256) void dist2_k(
    const u16* __restrict__ fh, const u16* __restrict__ gh,
    const float* __restrict__ fn, const float* __restrict__ gn,
    const float* __restrict__ p_eps, const float* __restrict__ p_sig,
    const float* __restrict__ p_sig0, const float* __restrict__ p_cst,
    u16* __restrict__ fm, double* __restrict__ colsumP,
    double* __restrict__ ss_parts)
{
  __shared__ float fnX[64], fnY[64], fnV[64], gnX[64], gnY[64], gnV[64];
  __shared__ float red[16][66];
  __shared__ float ssred[4];
  __shared__ u16 fmT[64][80];   // pad 80 -> conflict-free
  const int tid = threadIdx.x;
  const int w = tid >> 6, lane = tid & 63;
  const int m16 = lane & 15, quad = lane >> 4;
  // chunked bijective XCD swizzle (DBLK % 8 == 0): XCD k gets orig
  // [k*DBLK/8, (k+1)*DBLK/8) in order; orig is j-fast flattened.
  const int orig = (blockIdx.x & 7) * (DBLK / 8) + (blockIdx.x >> 3);
  const int it8 = orig >> 4;               // i-tile (0..511)
  const int i0 = it8 * 64, j0 = (orig & 15) * 64;

  if (tid < 64) {
    fnX[tid] = fn[i0 + tid]; fnY[tid] = fn[NXP + i0 + tid]; fnV[tid] = fn[2 * NXP + j0 + tid];
    gnX[tid] = gn[i0 + tid]; gnY[tid] = gn[NXP + i0 + tid]; gnV[tid] = gn[2 * NXP + j0 + tid];
  }

  f32x4 axf[4], ayf[4], axg[4], ayg[4];
#pragma unroll
  for (int nt = 0; nt < 4; ++nt) {
    axf[nt] = (f32x4)0.f; ayf[nt] = (f32x4)0.f;
    axg[nt] = (f32x4)0.f; ayg[nt] = (f32x4)0.f;
  }

  const int ixt = (i0 >> 4) + w;                // X tile for this wave
  const int iyt = ((NXP + i0) >> 4) + w;        // Y tile
  const int vt  = (2 * NXP + j0) >> 4;          // V tile base
#pragma unroll 1
  for (int ch = 0; ch < 4; ++ch) {
    f16x8 x = *reinterpret_cast<const f16x8*>(&fh[((size_t)(ixt * 4 + ch) * 64 + lane) * 8]);
    f16x8 y = *reinterpret_cast<const f16x8*>(&fh[((size_t)(iyt * 4 + ch) * 64 + lane) * 8]);
    f16x8 vh[4];
#pragma unroll
    for (int nt = 0; nt < 4; ++nt)
      vh[nt] = *reinterpret_cast<const f16x8*>(&fh[((size_t)((vt + nt) * 4 + ch) * 64 + lane) * 8]);
    __builtin_amdgcn_sched_barrier(0);
#pragma unroll
    for (int nt = 0; nt < 4; ++nt) {
      axf[nt] = __builtin_amdgcn_mfma_f32_16x16x32_f16(x, vh[nt], axf[nt], 0, 0, 0);
      ayf[nt] = __builtin_amdgcn_mfma_f32_16x16x32_f16(y, vh[nt], ayf[nt], 0, 0, 0);
    }
    __builtin_amdgcn_sched_barrier(0);
  }
  {
    f16x8 x = *reinterpret_cast<const f16x8*>(&gh[((size_t)ixt * 64 + lane) * 8]);
    f16x8 y = *reinterpret_cast<const f16x8*>(&gh[((size_t)iyt * 64 + lane) * 8]);
    f16x8 vh[4];
#pragma unroll
    for (int nt = 0; nt < 4; ++nt)
      vh[nt] = *reinterpret_cast<const f16x8*>(&gh[((size_t)(vt + nt) * 64 + lane) * 8]);
    __builtin_amdgcn_sched_barrier(0);
#pragma unroll
    for (int nt = 0; nt < 4; ++nt) {
      axg[nt] = __builtin_amdgcn_mfma_f32_16x16x32_f16(x, vh[nt], axg[nt], 0, 0, 0);
      ayg[nt] = __builtin_amdgcn_mfma_f32_16x16x32_f16(y, vh[nt], ayg[nt], 0, 0, 0);
    }
    __builtin_amdgcn_sched_barrier(0);
  }
  __syncthreads();   // norms ready

  float ep  = 1.f / (1.f + __expf(-p_eps[0]));
  float sg  = p_sig[0] * p_sig[0];
  float sg0 = p_sig0[0] * p_sig0[0];
  float cst = p_cst[0];
  float nis = -1.f / sg, nis0 = -1.f / sg0;
  float omep = 1.f - ep;
  float ss = 0.f;
  float colp[4] = {0.f, 0.f, 0.f, 0.f};
#pragma unroll
  for (int nt = 0; nt < 4; ++nt) {
    float fv = fnV[nt * 16 + m16], gv = gnV[nt * 16 + m16];
#pragma unroll
    for (int r = 0; r < 4; ++r) {
      int il = w * 16 + quad * 4 + r;
      float fx = fnX[il], fy = fnY[il], gx = gnX[il], gy = gnY[il];
      float dxf = fmaxf(fx + fv - 2.f * axf[nt][r], 0.f);
      float dxg = fmaxf(gx + gv - 2.f * axg[nt][r], 0.f);
      float dyf = fmaxf(fy + fv - 2.f * ayf[nt][r], 0.f);
      float dyg = fmaxf(gy + gv - 2.f * ayg[nt][r], 0.f);
      float kx = cst * (omep * __expf(dxf * nis0) + ep) * __expf(dxg * nis);
      float ky = cst * (omep * __expf(dyf * nis0) + ep) * __expf(dyg * nis);
      float fmv = (kx - ky) * 0.03125f;
      fmT[il][nt * 16 + m16] = (u16)(cvt_pk_bf16(fmv, fmv) & 0xFFFFu);
      ss = fmaf(fmv, fmv, ss);
      colp[nt] += fmv;
    }
  }
#pragma unroll
  for (int m = 32; m >= 1; m >>= 1) ss += __shfl_xor(ss, m);
  if (lane == 0) ssred[w] = ss;
#pragma unroll
  for (int nt = 0; nt < 4; ++nt) red[w * 4 + quad][nt * 16 + m16] = colp[nt];
  __syncthreads();
  // coalesced fm store: each thread 2x 16B chunks, 128B-line aligned rows
#pragma unroll
  for (int it = 0; it < 2; ++it) {
    int idx = tid + it * 256;
    int row = idx >> 3, c8 = (idx & 7) * 8;
    *reinterpret_cast<uint4*>(&fm[(size_t)(i0 + row) * NV + j0 + c8]) =
        *reinterpret_cast<const uint4*>(&fmT[row][c8]);
  }
  if (tid < 64) {
    float s = 0.f;
#pragma unroll
    for (int t = 0; t < 16; ++t) s += red[t][tid];
    atomicAdd(&colsumP[(size_t)(it8 & (CSTR - 1)) * NV + j0 + tid], (double)s);
  }
  if (tid == 0) {
    double v = (double)ssred[0] + ssred[1] + ssred[2] + ssred[3];
    atomicAdd(&ss_parts[it8 & 63], v);
  }
}

// ---------------------------------------------------------------------------
__global__ __launch_bounds__(256) void mu_k(
    const double* __restrict__ colsumP, float* __restrict__ mu,
    double* __restrict__ summu2)
{
  __shared__ double wred[4];
  double local = 0.0;
  for (int j = threadIdx.x; j < NV; j += 256) {
    double m = 0.0;
#pragma unroll 4
    for (int t = 0; t < CSTR; ++t) m += colsumP[(size_t)t * NV + j];
    m *= (1.0 / (double)NXP);
    mu[j] = (float)m;
    local += m * m;
  }
  int lane = threadIdx.x & 63, wave = threadIdx.x >> 6;
#pragma unroll
  for (int m = 32; m >= 1; m >>= 1) local += __shfl_xor(local, m);
  if (lane == 0) wred[wave] = local;
  __syncthreads();
  if (threadIdx.x == 0) *summu2 = wred[0] + wred[1] + wred[2] + wred[3];
}

// ---------------------------------------------------------------------------
// Pass 2 on bf16 fm: z_i = fm[i,:].mu ; sum z^2.
// ---------------------------------------------------------------------------
__global__ __launch_bounds__(256) void pass2_k(
    const u16* __restrict__ fm, const float* __restrict__ mu,
    double* __restrict__ sz_parts)
{
  __shared__ float mus[NV];
  for (int l = threadIdx.x; l < NV; l += 256) mus[l] = mu[l];
  __syncthreads();
  __shared__ double zb[4];
  int wave = threadIdx.x >> 6, lane = threadIdx.x & 63;
  int row = blockIdx.x * 4 + wave;
  const u16* frow = fm + (size_t)row * NV;
  float z = 0.f;
#pragma unroll
  for (int it = 0; it < 2; ++it) {
    int base = (lane + 64 * it) * 8;
    uint4 raw = *reinterpret_cast<const uint4*>(&frow[base]);
    const u16* v = reinterpret_cast<const u16*>(&raw);
#pragma unroll
    for (int k = 0; k < 8; ++k) z = fmaf(bf2f(v[k]), mus[base + k], z);
  }
#pragma unroll
  for (int m = 32; m >= 1; m >>= 1) z += __shfl_xor(z, m);
  if (lane == 0) zb[wave] = (double)z * (double)z;
  __syncthreads();
  if (threadIdx.x == 0)
    atomicAdd(&sz_parts[blockIdx.x & 63], zb[0] + zb[1] + zb[2] + zb[3]);
}

__global__ __launch_bounds__(64) void final_k(
    const double* __restrict__ ss_parts, const double* __restrict__ sz_parts,
    const double* __restrict__ summu2, float* __restrict__ out)
{
  int lane = threadIdx.x;
  double ss = ss_parts[lane], sz = sz_parts[lane];
#pragma unroll
  for (int m = 32; m >= 1; m >>= 1) { ss += __shfl_xor(ss, m); sz += __shfl_xor(sz, m); }
  if (lane == 0) {
    double smu2 = *summu2;
    const double nx = (double)NXP;
    double t1 = smu2 * nx / (nx - 1.0);
    double t2 = ss / (nx * (nx - 1.0));
    double um = t1 - t2;
    double uv = 4.0 * (sz / nx) - 4.0 * smu2 * smu2;
    out[0] = (float)(-(um / sqrt(uv + 1e-6)));
  }
}

// ---------------------------------------------------------------------------
extern "C" void kernel_launch(void* const* d_in, const int* in_sizes, int n_in,
                              void* d_out, int out_size, void* d_ws, size_t ws_size,
                              hipStream_t stream)
{
  (void)in_sizes; (void)n_in; (void)out_size; (void)ws_size;
  const float* XY = (const float*)d_in[0];
  const float* V  = (const float*)d_in[1];
  const float* dnW[6]; const float* dnb[6]; const float* anW[6]; const float* anb[6];
  for (int i = 0; i < 6; ++i) {
    dnW[i] = (const float*)d_in[2 + 2 * i];  dnb[i] = (const float*)d_in[3 + 2 * i];
    anW[i] = (const float*)d_in[14 + 2 * i]; anb[i] = (const float*)d_in[15 + 2 * i];
  }
  const float* p_eps  = (const float*)d_in[26];
  const float* p_sig  = (const float*)d_in[27];
  const float* p_sig0 = (const float*)d_in[28];
  const float* p_cst  = (const float*)d_in[29];

  char* base = (char*)d_ws;
  size_t off = 0;
  auto alloc = [&](size_t b) { size_t o = off; off += (b + 255) & ~(size_t)255; return o; };
  float* Xf    = (float*)(base + alloc((size_t)NROW * GD * 4));
  u16*   Xhi   = (u16*)  (base + alloc((size_t)NROW * 32 * 2));
  float* fn    = (float*)(base + alloc((size_t)NROW * 4));
  float* gn    = (float*)(base + alloc((size_t)NROW * 4));
  float* mu    = (float*)(base + alloc((size_t)NV * 4));
  size_t zoff = off;
  double* colsumP  = (double*)(base + alloc((size_t)CSTR * NV * 8));
  double* ss_parts = (double*)(base + alloc(64 * 8));
  double* sz_parts = (double*)(base + alloc(64 * 8));
  double* summu2   = (double*)(base + alloc(8));
  size_t zbytes = off - zoff;
  u16* Whi = (u16*)(base + alloc((size_t)12 * HP * HP * 2));
  u16* fh  = (u16*)(base + alloc((size_t)NROW * FKP * 2));
  u16* gh  = (u16*)(base + alloc((size_t)NROW * GKP * 2));
  u16* fm  = (u16*)(base + alloc((size_t)NXP * NV * 2));   // bf16 fm

  PrepArgs pa;
  pa.XY = XY; pa.V = V; pa.Xhi = Xhi; pa.Xf = Xf;
  for (int i = 0; i < 6; ++i) {
    int K = (i == 0) ? GD : HD, M = (i == 5) ? FD : HD;
    int Kp = (i == 0) ? 32 : HP, Mp = (i == 5) ? 128 : HP;
    pa.d[i] = {dnW[i], dnb[i], Whi + (size_t)i * HP * HP, K, M, Kp, Mp};
  }
  for (int i = 0; i < 6; ++i) {
    int K = (i == 0) ? GD : HD, M = (i == 5) ? GD : HD;
    int Kp = (i == 0) ? 32 : HP, Mp = (i == 5) ? 64 : HP;
    pa.d[6 + i] = {anW[i], anb[i], Whi + (size_t)(6 + i) * HP * HP, K, M, Kp, Mp};
  }
  pa.zbase = base + zoff; pa.zbytes = (unsigned)zbytes;

  const int nzblk = (int)((zbytes / 16 + 255) / 256);
  prep_all<<<NXBLK + 12 * NWBLK + nzblk, dim3(256), 0, stream>>>(pa);

  const int nchunk = (NROW + SAMP - 1) / SAMP;   // 694, last chunk overlaps (idempotent)
  mlp_fused<<<2 * nchunk, dim3(512), 0, stream>>>(Xhi, Xf, Whi, fh, gh, fn, gn);

  dist2_k<<<dim3(DBLK), dim3(256), 0, stream>>>(
      fh, gh, fn, gn, p_eps, p_sig, p_sig0, p_cst,
      fm, colsumP, ss_parts);
  mu_k<<<1, dim3(256), 0, stream>>>(colsumP, mu, summu2);
  pass2_k<<<NXP / 4, dim3(256), 0, stream>>>(fm, mu, sz_parts);
  final_k<<<1, 64, 0, stream>>>(ss_parts, sz_parts, summu2, (float*)d_out);
}

// Round 19
// 333.919 us; speedup vs baseline: 1.0905x; 1.0905x over previous
//
#include <hip/hip_runtime.h>
#include <cstdint>

#define NROW 66560   // 2*NX + J rows through both MLPs
#define NXP  32768   // nx
#define NV   1024    // J
#define FD   100     // dn output dim
#define GD   28      // input / an output dim
#define HD   300     // hidden dim
#define HP   320     // padded hidden dim
#define SAMP 96      // samples per block (MLP)
#define NT   6       // sample tiles
#define NCH  10      // K chunks (320/32)
#define FKP  128     // f padded K for dist MFMA
#define GKP  32      // g padded K
#define CSTR 32      // colsum stripes
#define NXBLK (NROW * 32 / 256)   // 8320 prep_x blocks
#define NWBLK 400                 // blocks per weight matrix (102400/256)

typedef unsigned short u16;
typedef __bf16    bf16x8 __attribute__((ext_vector_type(8)));
typedef _Float16  f16x8  __attribute__((ext_vector_type(8)));
typedef float     f32x4  __attribute__((ext_vector_type(4)));

__device__ inline u16 f2bf(float x) {
  unsigned u = __builtin_bit_cast(unsigned, x);
  unsigned r = (u + 0x7FFF + ((u >> 16) & 1)) >> 16;
  return (u16)r;
}
__device__ inline float bf2f(u16 h) {
  unsigned u = ((unsigned)h) << 16;
  return __builtin_bit_cast(float, u);
}
// HW packed f32->bf16 RNE.
__device__ inline unsigned cvt_pk_bf16(float lo, float hi) {
  unsigned r;
  asm("v_cvt_pk_bf16_f32 %0, %1, %2" : "=v"(r) : "v"(lo), "v"(hi));
  return r;
}
// RNE f32->fp16 pair pack.
__device__ inline unsigned pk_f16(float a, float b) {
  unsigned ua = (unsigned)__builtin_bit_cast(u16, (_Float16)a);
  unsigned ub = (unsigned)__builtin_bit_cast(u16, (_Float16)b);
  return ua | (ub << 16);
}
__device__ inline float f16tof(u16 h) {
  return (float)__builtin_bit_cast(_Float16, h);
}

// ---------------------------------------------------------------------------
// prep_all: fused prep_x + prep_w + zero-fill. All MLP planes fp16.
// BIAS-FOLD: weight row k==K holds bias[m]; activation col K holds 1.0.
// ---------------------------------------------------------------------------
struct WDesc { const float* W; const float* b; u16* hi; int K, M, Kpad, Mpad; };
struct PrepArgs {
  const float* XY; const float* V; u16* Xhi; float* Xf;
  WDesc d[12];
  char* zbase; unsigned zbytes;
};

__global__ __launch_bounds__(256) void prep_all(PrepArgs a)
{
  const int tid = threadIdx.x;
  const int bid = blockIdx.x;
  if (bid < NXBLK) {
    int gid = bid * 256 + tid;
    int row = gid >> 5, k = gid & 31;
    if (row >= NROW) return;
    float v = 0.f;
    if (k < GD) v = (row < 2 * NXP) ? a.XY[(size_t)row * GD + k]
                                    : a.V[(size_t)(row - 2 * NXP) * GD + k];
    else if (k == GD) v = 1.f;   // bias column for layer 0/6
    size_t off = (size_t)(row >> 4) * 512 + (size_t)(k >> 3) * 128
               + (size_t)(row & 15) * 8 + (k & 7);
    a.Xhi[off] = __builtin_bit_cast(u16, (_Float16)v);
    if (k < GD) a.Xf[(size_t)row * GD + k] = v;
  } else if (bid < NXBLK + 12 * NWBLK) {
    int r = bid - NXBLK;
    WDesc d = a.d[r / NWBLK];
    int gid = (r % NWBLK) * 256 + tid;
    if (gid >= d.Kpad * d.Mpad) return;
    int e = gid & 7, l = (gid >> 3) & 63, rest = gid >> 9;
    int nch = d.Kpad >> 5;
    int ch = rest % nch, t = rest / nch;
    int m = t * 16 + (l & 15);
    int k = ch * 32 + (l >> 4) * 8 + e;
    float v = 0.f;
    if (m < d.M) {
      if (k < d.K)       v = d.W[(size_t)k * d.M + m];
      else if (k == d.K) v = d.b[m];          // folded bias row
    }
    d.hi[gid] = __builtin_bit_cast(u16, (_Float16)v);
  } else {
    int r = bid - NXBLK - 12 * NWBLK;
    size_t off16 = ((size_t)r * 256 + tid) * 16;
    if (off16 < a.zbytes) {
      uint4 z = {0u, 0u, 0u, 0u};
      *reinterpret_cast<uint4*>(a.zbase + off16) = z;
    }
  }
}

// ---------------------------------------------------------------------------
// Fused MLP v21 (proven, 125us): fp16 interior + bias-folded weights.
// ---------------------------------------------------------------------------
template<int MT>
__device__ __forceinline__ void mm6(
    const u16* __restrict__ Wh, const u16* aH,
    f32x4 (&acc)[3][NT], int tile0, int lane)
{
#pragma unroll
  for (int mt = 0; mt < MT; ++mt)
#pragma unroll
    for (int nt = 0; nt < NT; ++nt) acc[mt][nt] = (f32x4)0.f;
#pragma unroll 2
  for (int ch = 0; ch < NCH; ++ch) {
    f16x8 wh[MT];
#pragma unroll
    for (int mt = 0; mt < MT; ++mt) {
      size_t wo = ((size_t)((tile0 + mt) * NCH + ch) * 64 + lane) * 8;
      wh[mt] = *reinterpret_cast<const f16x8*>(&Wh[wo]);
    }
#pragma unroll
    for (int g = 0; g < 3; ++g) {
      f16x8 bh[2];
#pragma unroll
      for (int n2 = 0; n2 < 2; ++n2)
        bh[n2] = *reinterpret_cast<const f16x8*>(
            &aH[(((g * 2 + n2) * NCH + ch) * 64 + lane) * 8]);
#pragma unroll
      for (int mt = 0; mt < MT; ++mt)
#pragma unroll
        for (int n2 = 0; n2 < 2; ++n2)
          acc[mt][g * 2 + n2] = __builtin_amdgcn_mfma_f32_16x16x32_f16(wh[mt], bh[n2], acc[mt][g * 2 + n2], 0, 0, 0);
    }
  }
}

template<int MT>
__device__ __forceinline__ void mm6_in(
    const u16* __restrict__ Wh,
    const u16* __restrict__ Xhi, int rowt0,
    f32x4 (&acc)[3][NT], int tile0, int lane)
{
#pragma unroll
  for (int mt = 0; mt < MT; ++mt)
#pragma unroll
    for (int nt = 0; nt < NT; ++nt) acc[mt][nt] = (f32x4)0.f;
  f16x8 wh[MT];
#pragma unroll
  for (int mt = 0; mt < MT; ++mt) {
    size_t wo = ((size_t)(tile0 + mt) * 64 + lane) * 8;
    wh[mt] = *reinterpret_cast<const f16x8*>(&Wh[wo]);
  }
#pragma unroll
  for (int g = 0; g < 3; ++g) {
    f16x8 bh[2];
#pragma unroll
    for (int n2 = 0; n2 < 2; ++n2) {
      int st = g * 2 + n2;
      bh[n2] = *reinterpret_cast<const f16x8*>(&Xhi[((size_t)(rowt0 + st) * 64 + lane) * 8]);
    }
#pragma unroll
    for (int mt = 0; mt < MT; ++mt)
#pragma unroll
      for (int n2 = 0; n2 < 2; ++n2)
        acc[mt][g * 2 + n2] = __builtin_amdgcn_mfma_f32_16x16x32_f16(wh[mt], bh[n2], acc[mt][g * 2 + n2], 0, 0, 0);
  }
}

// Epilogue: ReLU + fp16 pack only (bias folded). feat==HD gets 1.0.
template<int MT>
__device__ __forceinline__ void epi6(
    f32x4 (&acc)[3][NT],
    u16* aH, int tile0, int m16, int quad)
{
#pragma unroll
  for (int mt = 0; mt < MT; ++mt) {
    int T = tile0 + mt;
    int ch = T >> 1;
    int lfrag = m16 + 16 * ((T & 1) * 2 + (quad >> 1));
    int e0 = (quad & 1) * 4;
    bool biasCol = (T * 16 + quad * 4 == HD);   // feat 300 in this pack's r=0
#pragma unroll
    for (int nt = 0; nt < NT; ++nt) {
      uint2 d;
      d.x = pk_f16(fmaxf(acc[mt][nt][0], 0.f), fmaxf(acc[mt][nt][1], 0.f));
      d.y = pk_f16(fmaxf(acc[mt][nt][2], 0.f), fmaxf(acc[mt][nt][3], 0.f));
      if (biasCol) d.x = (d.x & 0xFFFF0000u) | 0x3C00u;   // feat 300 = 1.0
      *reinterpret_cast<uint2*>(&aH[((nt * NCH + ch) * 64 + lfrag) * 8 + e0]) = d;
    }
  }
}

__global__ __launch_bounds__(512, 4) void mlp_fused(
    const u16* __restrict__ Xhi, const float* __restrict__ Xf,
    const u16* __restrict__ Whi,
    u16* __restrict__ fh, u16* __restrict__ gh,
    float* __restrict__ fn, float* __restrict__ gn)
{
  __shared__ u16 aH[NT * NCH * 64 * 8];   // 61,440 B
  __shared__ float nP[8][SAMP];           // +3,072 B -> 64.5KB: 2 blocks/CU
  const int tid  = threadIdx.x;
  const int wave = tid >> 6, lane = tid & 63;
  const int m16  = lane & 15, quad = lane >> 4;
  const int half  = blockIdx.x & 1;          // 0 = dn MLP, 1 = an MLP
  const int chunk = blockIdx.x >> 1;
  const int row0 = (chunk * SAMP + SAMP <= NROW) ? chunk * SAMP
                                                 : NROW - SAMP;  // overlap-safe
  const int rowt0  = row0 >> 4;
  const int ftile0 = (wave < 4) ? wave * 48 : 192 + (wave - 4) * 32;
  const int tile0  = ftile0 >> 4;

  auto W = [&](int s) { return Whi + (size_t)s * HP * HP; };

  f32x4 acc[3][NT];

  if (half == 0) {
    // ---- dn MLP ----
    if (wave < 4) mm6_in<3>(W(0), Xhi, rowt0, acc, tile0, lane);
    else          mm6_in<2>(W(0), Xhi, rowt0, acc, tile0, lane);
    if (wave < 4) epi6<3>(acc, aH, tile0, m16, quad);
    else          epi6<2>(acc, aH, tile0, m16, quad);
    __syncthreads();
#pragma unroll 1
    for (int s = 1; s <= 4; ++s) {
      if (wave < 4) mm6<3>(W(s), aH, acc, tile0, lane);
      else          mm6<2>(W(s), aH, acc, tile0, lane);
      __syncthreads();
      if (wave < 4) epi6<3>(acc, aH, tile0, m16, quad);
      else          epi6<2>(acc, aH, tile0, m16, quad);
      __syncthreads();
    }
    // layer 5 + fused f-norms; store single fp16 f plane (bias folded)
    mm6<1>(W(5), aH, acc, wave, lane);
    int chf = wave >> 1;
    int lfrag = m16 + 16 * ((wave * 2 + (quad >> 1)) & 3);
    int e0 = (quad & 1) * 4;
#pragma unroll
    for (int nt = 0; nt < NT; ++nt) {
      uint2 hp;
      hp.x = pk_f16(acc[0][nt][0], acc[0][nt][1]);
      hp.y = pk_f16(acc[0][nt][2], acc[0][nt][3]);
      size_t o = ((size_t)((rowt0 + nt) * 4 + chf) * 64 + lfrag) * 8 + e0;
      *reinterpret_cast<uint2*>(&fh[o]) = hp;
      float a0 = f16tof((u16)(hp.x & 0xFFFF)), a1 = f16tof((u16)(hp.x >> 16));
      float a2 = f16tof((u16)(hp.y & 0xFFFF)), a3 = f16tof((u16)(hp.y >> 16));
      float pf = a0 * a0 + a1 * a1 + a2 * a2 + a3 * a3;
      pf += __shfl_xor(pf, 16);
      pf += __shfl_xor(pf, 32);
      if (quad == 0) nP[wave][nt * 16 + m16] = pf;
    }
    __syncthreads();
    if (tid < SAMP) {
      float s = 0.f;
#pragma unroll
      for (int w8 = 0; w8 < 8; ++w8) s += nP[w8][tid];
      fn[row0 + tid] = s;
    }
  } else {
    // ---- an MLP ----
    if (wave < 4) mm6_in<3>(W(6), Xhi, rowt0, acc, tile0, lane);
    else          mm6_in<2>(W(6), Xhi, rowt0, acc, tile0, lane);
    if (wave < 4) epi6<3>(acc, aH, tile0, m16, quad);
    else          epi6<2>(acc, aH, tile0, m16, quad);
    __syncthreads();
#pragma unroll 1
    for (int s = 7; s <= 10; ++s) {
      if (wave < 4) mm6<3>(W(s), aH, acc, tile0, lane);
      else          mm6<2>(W(s), aH, acc, tile0, lane);
      __syncthreads();
      if (wave < 4) epi6<3>(acc, aH, tile0, m16, quad);
      else          epi6<2>(acc, aH, tile0, m16, quad);
      __syncthreads();
    }
    // layer 11 + fused g-norms; store single fp16 g plane (bias folded)
    if (wave < 2) {
      mm6<1>(W(11), aH, acc, wave, lane);
      int c = wave * 16 + quad * 4;
      int lfrag = m16 + 16 * ((wave * 2 + (quad >> 1)) & 3);
      int e0 = (quad & 1) * 4;
#pragma unroll
      for (int nt = 0; nt < NT; ++nt) {
        int samp = nt * 16 + m16;
        float x[4];
#pragma unroll
        for (int r = 0; r < 4; ++r) {
          int feat = c + r;
          x[r] = (feat < GD)
               ? acc[0][nt][r] + Xf[(size_t)(row0 + samp) * GD + feat]
               : 0.f;
        }
        uint2 hp;
        hp.x = pk_f16(x[0], x[1]);
        hp.y = pk_f16(x[2], x[3]);
        size_t o = ((size_t)(rowt0 + nt) * 64 + lfrag) * 8 + e0;
        *reinterpret_cast<uint2*>(&gh[o]) = hp;
        float a0 = f16tof((u16)(hp.x & 0xFFFF)), a1 = f16tof((u16)(hp.x >> 16));
        float a2 = f16tof((u16)(hp.y & 0xFFFF)), a3 = f16tof((u16)(hp.y >> 16));
        float pg = a0 * a0 + a1 * a1 + a2 * a2 + a3 * a3;
        pg += __shfl_xor(pg, 16);
        pg += __shfl_xor(pg, 32);
        if (quad == 0) nP[wave][nt * 16 + m16] = pg;
      }
    }
    __syncthreads();
    if (tid < SAMP) gn[row0 + tid] = nP[0][tid] + nP[1][tid];
  }
}

// ---------------------------------------------------------------------------
// Dist pass (proven): single fp16 planes, 2D grid.
// ---------------------------------------------------------------------------
__global__ __launch_bounds__(256) void dist2_k(
    const u16* __restrict__ fh, const u16* __restrict__ gh,
    const float* __restrict__ fn, const float* __restrict__ gn,
    const float* __restrict__ p_eps, const float* __restrict__ p_sig,
    const float* __restrict__ p_sig0, const float* __restrict__ p_cst,
    u16* __restrict__ fm, double* __restrict__ colsumP,
    double* __restrict__ ss_parts)
{
  __shared__ float fnX[64], fnY[64], fnV[64], gnX[64], gnY[64], gnV[64];
  __shared__ float red[16][66];
  __shared__ float ssred[4];
  __shared__ u16 fmT[64][80];   // pad 80 -> conflict-free
  const int tid = threadIdx.x;
  const int w = tid >> 6, lane = tid & 63;
  const int m16 = lane & 15, quad = lane >> 4;
  const int i0 = blockIdx.x * 64, j0 = blockIdx.y * 64;

  if (tid < 64) {
    fnX[tid] = fn[i0 + tid]; fnY[tid] = fn[NXP + i0 + tid]; fnV[tid] = fn[2 * NXP + j0 + tid];
    gnX[tid] = gn[i0 + tid]; gnY[tid] = gn[NXP + i0 + tid]; gnV[tid] = gn[2 * NXP + j0 + tid];
  }

  f32x4 axf[4], ayf[4], axg[4], ayg[4];
#pragma unroll
  for (int nt = 0; nt < 4; ++nt) {
    axf[nt] = (f32x4)0.f; ayf[nt] = (f32x4)0.f;
    axg[nt] = (f32x4)0.f; ayg[nt] = (f32x4)0.f;
  }

  const int ixt = (i0 >> 4) + w;                // X tile for this wave
  const int iyt = ((NXP + i0) >> 4) + w;        // Y tile
  const int vt  = (2 * NXP + j0) >> 4;          // V tile base
#pragma unroll 1
  for (int ch = 0; ch < 4; ++ch) {
    f16x8 x = *reinterpret_cast<const f16x8*>(&fh[((size_t)(ixt * 4 + ch) * 64 + lane) * 8]);
    f16x8 y = *reinterpret_cast<const f16x8*>(&fh[((size_t)(iyt * 4 + ch) * 64 + lane) * 8]);
    f16x8 vh[4];
#pragma unroll
    for (int nt = 0; nt < 4; ++nt)
      vh[nt] = *reinterpret_cast<const f16x8*>(&fh[((size_t)((vt + nt) * 4 + ch) * 64 + lane) * 8]);
    __builtin_amdgcn_sched_barrier(0);
#pragma unroll
    for (int nt = 0; nt < 4; ++nt) {
      axf[nt] = __builtin_amdgcn_mfma_f32_16x16x32_f16(x, vh[nt], axf[nt], 0, 0, 0);
      ayf[nt] = __builtin_amdgcn_mfma_f32_16x16x32_f16(y, vh[nt], ayf[nt], 0, 0, 0);
    }
    __builtin_amdgcn_sched_barrier(0);
  }
  {
    f16x8 x = *reinterpret_cast<const f16x8*>(&gh[((size_t)ixt * 64 + lane) * 8]);
    f16x8 y = *reinterpret_cast<const f16x8*>(&gh[((size_t)iyt * 64 + lane) * 8]);
    f16x8 vh[4];
#pragma unroll
    for (int nt = 0; nt < 4; ++nt)
      vh[nt] = *reinterpret_cast<const f16x8*>(&gh[((size_t)(vt + nt) * 64 + lane) * 8]);
    __builtin_amdgcn_sched_barrier(0);
#pragma unroll
    for (int nt = 0; nt < 4; ++nt) {
      axg[nt] = __builtin_amdgcn_mfma_f32_16x16x32_f16(x, vh[nt], axg[nt], 0, 0, 0);
      ayg[nt] = __builtin_amdgcn_mfma_f32_16x16x32_f16(y, vh[nt], ayg[nt], 0, 0, 0);
    }
    __builtin_amdgcn_sched_barrier(0);
  }
  __syncthreads();   // norms ready

  float ep  = 1.f / (1.f + __expf(-p_eps[0]));
  float sg  = p_sig[0] * p_sig[0];
  float sg0 = p_sig0[0] * p_sig0[0];
  float cst = p_cst[0];
  float nis = -1.f / sg, nis0 = -1.f / sg0;
  float omep = 1.f - ep;
  float ss = 0.f;
  float colp[4] = {0.f, 0.f, 0.f, 0.f};
#pragma unroll
  for (int nt = 0; nt < 4; ++nt) {
    float fv = fnV[nt * 16 + m16], gv = gnV[nt * 16 + m16];
#pragma unroll
    for (int r = 0; r < 4; ++r) {
      int il = w * 16 + quad * 4 + r;
      float fx = fnX[il], fy = fnY[il], gx = gnX[il], gy = gnY[il];
      float dxf = fmaxf(fx + fv - 2.f * axf[nt][r], 0.f);
      float dxg = fmaxf(gx + gv - 2.f * axg[nt][r], 0.f);
      float dyf = fmaxf(fy + fv - 2.f * ayf[nt][r], 0.f);
      float dyg = fmaxf(gy + gv - 2.f * ayg[nt][r], 0.f);
      float kx = cst * (omep * __expf(dxf * nis0) + ep) * __expf(dxg * nis);
      float ky = cst * (omep * __expf(dyf * nis0) + ep) * __expf(dyg * nis);
      float fmv = (kx - ky) * 0.03125f;
      fmT[il][nt * 16 + m16] = (u16)(cvt_pk_bf16(fmv, fmv) & 0xFFFFu);
      ss = fmaf(fmv, fmv, ss);
      colp[nt] += fmv;
    }
  }
#pragma unroll
  for (int m = 32; m >= 1; m >>= 1) ss += __shfl_xor(ss, m);
  if (lane == 0) ssred[w] = ss;
#pragma unroll
  for (int nt = 0; nt < 4; ++nt) red[w * 4 + quad][nt * 16 + m16] = colp[nt];
  __syncthreads();
  // coalesced fm store: each thread 2x 16B chunks, 128B-line aligned rows
#pragma unroll
  for (int it = 0; it < 2; ++it) {
    int idx = tid + it * 256;
    int row = idx >> 3, c8 = (idx & 7) * 8;
    *reinterpret_cast<uint4*>(&fm[(size_t)(i0 + row) * NV + j0 + c8]) =
        *reinterpret_cast<const uint4*>(&fmT[row][c8]);
  }
  if (tid < 64) {
    float s = 0.f;
#pragma unroll
    for (int t = 0; t < 16; ++t) s += red[t][tid];
    atomicAdd(&colsumP[(size_t)(blockIdx.x & (CSTR - 1)) * NV + j0 + tid], (double)s);
  }
  if (tid == 0) {
    double v = (double)ssred[0] + ssred[1] + ssred[2] + ssred[3];
    atomicAdd(&ss_parts[blockIdx.x & 63], v);
  }
}

// ---------------------------------------------------------------------------
__global__ __launch_bounds__(256) void mu_k(
    const double* __restrict__ colsumP, float* __restrict__ mu,
    double* __restrict__ summu2)
{
  __shared__ double wred[4];
  double local = 0.0;
  for (int j = threadIdx.x; j < NV; j += 256) {
    double m = 0.0;
#pragma unroll 4
    for (int t = 0; t < CSTR; ++t) m += colsumP[(size_t)t * NV + j];
    m *= (1.0 / (double)NXP);
    mu[j] = (float)m;
    local += m * m;
  }
  int lane = threadIdx.x & 63, wave = threadIdx.x >> 6;
#pragma unroll
  for (int m = 32; m >= 1; m >>= 1) local += __shfl_xor(local, m);
  if (lane == 0) wred[wave] = local;
  __syncthreads();
  if (threadIdx.x == 0) *summu2 = wred[0] + wred[1] + wred[2] + wred[3];
}

// ---------------------------------------------------------------------------
// Pass 2 on bf16 fm: z_i = fm[i,:].mu ; sum z^2.
// ---------------------------------------------------------------------------
__global__ __launch_bounds__(256) void pass2_k(
    const u16* __restrict__ fm, const float* __restrict__ mu,
    double* __restrict__ sz_parts)
{
  __shared__ float mus[NV];
  for (int l = threadIdx.x; l < NV; l += 256) mus[l] = mu[l];
  __syncthreads();
  __shared__ double zb[4];
  int wave = threadIdx.x >> 6, lane = threadIdx.x & 63;
  int row = blockIdx.x * 4 + wave;
  const u16* frow = fm + (size_t)row * NV;
  float z = 0.f;
#pragma unroll
  for (int it = 0; it < 2; ++it) {
    int base = (lane + 64 * it) * 8;
    uint4 raw = *reinterpret_cast<const uint4*>(&frow[base]);
    const u16* v = reinterpret_cast<const u16*>(&raw);
#pragma unroll
    for (int k = 0; k < 8; ++k) z = fmaf(bf2f(v[k]), mus[base + k], z);
  }
#pragma unroll
  for (int m = 32; m >= 1; m >>= 1) z += __shfl_xor(z, m);
  if (lane == 0) zb[wave] = (double)z * (double)z;
  __syncthreads();
  if (threadIdx.x == 0)
    atomicAdd(&sz_parts[blockIdx.x & 63], zb[0] + zb[1] + zb[2] + zb[3]);
}

__global__ __launch_bounds__(64) void final_k(
    const double* __restrict__ ss_parts, const double* __restrict__ sz_parts,
    const double* __restrict__ summu2, float* __restrict__ out)
{
  int lane = threadIdx.x;
  double ss = ss_parts[lane], sz = sz_parts[lane];
#pragma unroll
  for (int m = 32; m >= 1; m >>= 1) { ss += __shfl_xor(ss, m); sz += __shfl_xor(sz, m); }
  if (lane == 0) {
    double smu2 = *summu2;
    const double nx = (double)NXP;
    double t1 = smu2 * nx / (nx - 1.0);
    double t2 = ss / (nx * (nx - 1.0));
    double um = t1 - t2;
    double uv = 4.0 * (sz / nx) - 4.0 * smu2 * smu2;
    out[0] = (float)(-(um / sqrt(uv + 1e-6)));
  }
}

// ---------------------------------------------------------------------------
extern "C" void kernel_launch(void* const* d_in, const int* in_sizes, int n_in,
                              void* d_out, int out_size, void* d_ws, size_t ws_size,
                              hipStream_t stream)
{
  (void)in_sizes; (void)n_in; (void)out_size; (void)ws_size;
  const float* XY = (const float*)d_in[0];
  const float* V  = (const float*)d_in[1];
  const float* dnW[6]; const float* dnb[6]; const float* anW[6]; const float* anb[6];
  for (int i = 0; i < 6; ++i) {
    dnW[i] = (const float*)d_in[2 + 2 * i];  dnb[i] = (const float*)d_in[3 + 2 * i];
    anW[i] = (const float*)d_in[14 + 2 * i]; anb[i] = (const float*)d_in[15 + 2 * i];
  }
  const float* p_eps  = (const float*)d_in[26];
  const float* p_sig  = (const float*)d_in[27];
  const float* p_sig0 = (const float*)d_in[28];
  const float* p_cst  = (const float*)d_in[29];

  char* base = (char*)d_ws;
  size_t off = 0;
  auto alloc = [&](size_t b) { size_t o = off; off += (b + 255) & ~(size_t)255; return o; };
  float* Xf    = (float*)(base + alloc((size_t)NROW * GD * 4));
  u16*   Xhi   = (u16*)  (base + alloc((size_t)NROW * 32 * 2));
  float* fn    = (float*)(base + alloc((size_t)NROW * 4));
  float* gn    = (float*)(base + alloc((size_t)NROW * 4));
  float* mu    = (float*)(base + alloc((size_t)NV * 4));
  size_t zoff = off;
  double* colsumP  = (double*)(base + alloc((size_t)CSTR * NV * 8));
  double* ss_parts = (double*)(base + alloc(64 * 8));
  double* sz_parts = (double*)(base + alloc(64 * 8));
  double* summu2   = (double*)(base + alloc(8));
  size_t zbytes = off - zoff;
  u16* Whi = (u16*)(base + alloc((size_t)12 * HP * HP * 2));
  u16* fh  = (u16*)(base + alloc((size_t)NROW * FKP * 2));
  u16* gh  = (u16*)(base + alloc((size_t)NROW * GKP * 2));
  u16* fm  = (u16*)(base + alloc((size_t)NXP * NV * 2));   // bf16 fm

  PrepArgs pa;
  pa.XY = XY; pa.V = V; pa.Xhi = Xhi; pa.Xf = Xf;
  for (int i = 0; i < 6; ++i) {
    int K = (i == 0) ? GD : HD, M = (i == 5) ? FD : HD;
    int Kp = (i == 0) ? 32 : HP, Mp = (i == 5) ? 128 : HP;
    pa.d[i] = {dnW[i], dnb[i], Whi + (size_t)i * HP * HP, K, M, Kp, Mp};
  }
  for (int i = 0; i < 6; ++i) {
    int K = (i == 0) ? GD : HD, M = (i == 5) ? GD : HD;
    int Kp = (i == 0) ? 32 : HP, Mp = (i == 5) ? 64 : HP;
    pa.d[6 + i] = {anW[i], anb[i], Whi + (size_t)(6 + i) * HP * HP, K, M, Kp, Mp};
  }
  pa.zbase = base + zoff; pa.zbytes = (unsigned)zbytes;

  const int nzblk = (int)((zbytes / 16 + 255) / 256);
  prep_all<<<NXBLK + 12 * NWBLK + nzblk, dim3(256), 0, stream>>>(pa);

  const int nchunk = (NROW + SAMP - 1) / SAMP;   // 694, last chunk overlaps (idempotent)
  mlp_fused<<<2 * nchunk, dim3(512), 0, stream>>>(Xhi, Xf, Whi, fh, gh, fn, gn);

  dist2_k<<<dim3(NXP / 64, NV / 64), dim3(256), 0, stream>>>(
      fh, gh, fn, gn, p_eps, p_sig, p_sig0, p_cst,
      fm, colsumP, ss_parts);
  mu_k<<<1, dim3(256), 0, stream>>>(colsumP, mu, summu2);
  pass2_k<<<NXP / 4, dim3(256), 0, stream>>>(fm, mu, sz_parts);
  final_k<<<1, 64, 0, stream>>>(ss_parts, sz_parts, summu2, (float*)d_out);
}